// Round 8
// baseline (387.856 us; speedup 1.0000x reference)
//
#include <hip/hip_runtime.h>
#include <hip/hip_bf16.h>

// Problem constants (B,R,M,L,H) = (256, 2048, 65536, 64, 4)
#define BB   256
#define RR   2048
#define MM   65536
#define LL   64
#define HH   4
#define NROW 1024      // B*H rows
#define KEYS 256       // H*L

typedef float f32x4 __attribute__((ext_vector_type(4)));
typedef short short8 __attribute__((ext_vector_type(8)));

#define MFMA(A,B,C) __builtin_amdgcn_mfma_f32_16x16x32_bf16((A),(B),(C),0,0,0)
#define LOG2E 1.4426950408889634f
#define EXP2F(x) __builtin_amdgcn_exp2f(x)

// ---- bf16 round-nearest-even split helpers ----
__device__ __forceinline__ unsigned short bf16_rn(float x) {
    union { float f; unsigned int u; } v; v.f = x;
    unsigned int r = v.u + 0x7FFFu + ((v.u >> 16) & 1u);
    return (unsigned short)(r >> 16);
}
__device__ __forceinline__ float bf16_to_f(unsigned short h) {
    union { float f; unsigned int u; } v; v.u = ((unsigned int)h) << 16; return v.f;
}
__device__ __forceinline__ void split8_store(const float* x, unsigned short* hi, unsigned short* lo) {
    unsigned int ph[4], pl[4];
#pragma unroll
    for (int j = 0; j < 4; ++j) {
        unsigned short h0 = bf16_rn(x[2*j]),   l0 = bf16_rn(x[2*j]   - bf16_to_f(h0));
        unsigned short h1 = bf16_rn(x[2*j+1]), l1 = bf16_rn(x[2*j+1] - bf16_to_f(h1));
        ph[j] = (unsigned int)h0 | ((unsigned int)h1 << 16);
        pl[j] = (unsigned int)l0 | ((unsigned int)l1 << 16);
    }
    ((uint4*)hi)[0] = make_uint4(ph[0], ph[1], ph[2], ph[3]);
    ((uint4*)lo)[0] = make_uint4(pl[0], pl[1], pl[2], pl[3]);
}
// in-register variant: identical math -> bitwise-identical fragments
__device__ __forceinline__ void split8_reg(const float* x, short8& hi, short8& lo) {
    union { unsigned int u[4]; short8 s; } H, L;
#pragma unroll
    for (int j = 0; j < 4; ++j) {
        unsigned short h0 = bf16_rn(x[2*j]),   l0 = bf16_rn(x[2*j]   - bf16_to_f(h0));
        unsigned short h1 = bf16_rn(x[2*j+1]), l1 = bf16_rn(x[2*j+1] - bf16_to_f(h1));
        H.u[j] = (unsigned int)h0 | ((unsigned int)h1 << 16);
        L.u[j] = (unsigned int)l0 | ((unsigned int)l1 << 16);
    }
    hi = H.s; lo = L.s;
}

// ================= SETUP: blocks 0..511 = prep_mem, 512..767 = k0_keys ==========
__global__ __launch_bounds__(256) void setup_k(const float* __restrict__ mem,
                                               const float* __restrict__ Wk,
                                               const float* __restrict__ S,
                                               unsigned short* __restrict__ bhi,
                                               unsigned short* __restrict__ blo,
                                               float* __restrict__ normpart,
                                               float* __restrict__ kpart) {
    __shared__ float sh[18496];   // max(prep_mem: 8704+128, k0: 2048+16448) floats
    int bx = blockIdx.x, tid = threadIdx.x;
    if (bx < 512) {
        // ---------------- prep_mem ----------------
        float* t     = sh;            // [128][68]
        float* rowsq = sh + 128 * 68; // [128]
        int blk = bx;
        const f32x4* src = (const f32x4*)(mem + (size_t)blk * 128 * LL);
#pragma unroll
        for (int i = 0; i < 8; ++i) {
            int idx = i * 256 + tid;              // flat float4 index
            int row = idx >> 4, c4 = idx & 15;
            *(f32x4*)&t[row * 68 + c4 * 4] = src[idx];
        }
        __syncthreads();
        if (tid < 128) {
            const float* rp = t + tid * 68;
            float s = 0.f;
#pragma unroll
            for (int k = 0; k < 64; ++k) s = fmaf(rp[k], rp[k], s);
            rowsq[tid] = s;
        }
        __syncthreads();
        if (tid < 64) {
            float m = fmaxf(rowsq[tid], rowsq[tid + 64]);
#pragma unroll
            for (int off = 1; off < 64; off <<= 1) m = fmaxf(m, __shfl_xor(m, off, 64));
            if (tid == 0) normpart[blk] = m;
        }
#pragma unroll
        for (int i = 0; i < 4; ++i) {
            int slot = i * 256 + tid;
            int lane = slot & 63, frag_l = slot >> 6;   // frag_l 0..15
            int t_l = frag_l >> 1, c = frag_l & 1;
            int row = t_l * 16 + (lane & 15);
            int k0 = c * 32 + (lane >> 4) * 8;
            const float* p = t + row * 68 + k0;
            float x[8];
#pragma unroll
            for (int j = 0; j < 8; ++j) x[j] = p[j];
            size_t gslot = ((size_t)blk * 16 + frag_l) * 64 + lane;
            split8_store(x, bhi + gslot * 8, blo + gslot * 8);
        }
    } else {
        // ---------------- k0 keys GEMM (transpose fused) ----------------
        float* sl = sh;            // [8][256] staged S rows
        float* wk = sh + 2048;     // [64][257] transposed Wk sub-tile
        int bx2 = bx - 512;
        int bg = bx2 >> 3, kc = bx2 & 7;
        int b0 = bg * 8;
#pragma unroll
        for (int bi = 0; bi < 8; ++bi)
            sl[bi * 256 + tid] = S[(size_t)(b0 + bi) * RR + kc * 256 + tid];
        float acc[8] = {0,0,0,0,0,0,0,0};
        for (int sub = 0; sub < 4; ++sub) {
            const f32x4* wsrc = (const f32x4*)(Wk + (size_t)tid * RR + kc * 256 + sub * 64);
#pragma unroll
            for (int i = 0; i < 16; ++i) {
                f32x4 v = wsrc[i];
#pragma unroll
                for (int q = 0; q < 4; ++q)
                    wk[(i * 4 + q) * 257 + tid] = v[q];
            }
            __syncthreads();
#pragma unroll 4
            for (int kkl = 0; kkl < 64; ++kkl) {
                float wv = wk[kkl * 257 + tid];
                int kk = sub * 64 + kkl;
#pragma unroll
                for (int bi = 0; bi < 8; ++bi)
                    acc[bi] = fmaf(sl[bi * 256 + kk], wv, acc[bi]);
            }
            __syncthreads();
        }
        float* op = kpart + (size_t)kc * BB * KEYS + (size_t)b0 * KEYS + tid;
#pragma unroll
        for (int bi = 0; bi < 8; ++bi)
            op[bi * KEYS] = acc[bi];
    }
}

// ---------------- K1: beta, key norm, q_rm = keys*beta*log2e/norm, brow = beta*maxnorm*log2e ----
__global__ __launch_bounds__(256) void k1_finalize(const float* __restrict__ S,
                                                   const float* __restrict__ kpart,
                                                   const float* __restrict__ bk,
                                                   const float* __restrict__ Wb,
                                                   const float* __restrict__ bb,
                                                   const float* __restrict__ normpart,
                                                   float* __restrict__ q_rm,
                                                   float* __restrict__ brow) {
    int bh = blockIdx.x, b = bh >> 2, h = bh & 3;
    int tid = threadIdx.x, lane = tid & 63, w = tid >> 6;
    float p = 0.f;
#pragma unroll
    for (int i = 0; i < 8; ++i) {
        int k = i * 256 + tid;
        p += S[(size_t)b * RR + k] * Wb[(size_t)h * RR + k];
    }
    float nm = fmaxf(normpart[tid], normpart[256 + tid]);   // 512 partials
#pragma unroll
    for (int off = 1; off < 64; off <<= 1) {
        p  += __shfl_xor(p, off, 64);
        nm  = fmaxf(nm, __shfl_xor(nm, off, 64));
    }
    __shared__ float red[4], redm[4];
    if (lane == 0) { red[w] = p; redm[w] = nm; }
    __syncthreads();
    if (tid < 64) {
        float beta = red[0] + red[1] + red[2] + red[3] + bb[h];
        beta = fmaxf(beta, 0.f);
        float maxn = sqrtf(fmaxf(fmaxf(redm[0], redm[1]), fmaxf(redm[2], redm[3])));
        float kv = bk[h * LL + lane];
#pragma unroll
        for (int c = 0; c < 8; ++c)
            kv += kpart[(size_t)c * BB * KEYS + (size_t)b * KEYS + h * LL + lane];
        float sq = kv * kv;
#pragma unroll
        for (int off = 1; off < 64; off <<= 1) sq += __shfl_xor(sq, off, 64);
        float scale = beta * LOG2E / sqrtf(sq);
        q_rm[(size_t)bh * LL + lane] = kv * scale;
        if (lane == 0) brow[bh] = beta * maxn * LOG2E;  // exact upper bound (Cauchy-Schwarz), log2 domain
    }
}

// XCD-chunked bijective swizzle for 1024 blocks (1024 % 8 == 0)
__device__ __forceinline__ void decode_wg(int bx, int& mblk, int& rg) {
    int wg = ((bx & 7) << 7) | (bx >> 3);
    mblk = wg >> 4; rg = wg & 15;
}

// ---------------- K2: split-bf16 MFMA dot + exp2(d - brow) partial row sums ----------
__global__ __launch_bounds__(256) void k2_mfma(const unsigned short* __restrict__ bhi,
                                               const unsigned short* __restrict__ blo,
                                               const float* __restrict__ q_rm,
                                               const float* __restrict__ brow,
                                               float* __restrict__ psum) {
    int mblk, rg; decode_wg(blockIdx.x, mblk, rg);
    int tid = threadIdx.x, w = tid >> 6, lane = tid & 63;
    int g = lane >> 4;
    short8 Ah[4][2], Al[4][2];
#pragma unroll
    for (int rt = 0; rt < 4; ++rt)
#pragma unroll
        for (int c = 0; c < 2; ++c) {
            const float* qp = q_rm + (size_t)(rg * 64 + rt * 16 + (lane & 15)) * LL
                              + c * 32 + (lane >> 4) * 8;
            f32x4 x0 = *(const f32x4*)qp, x1 = *(const f32x4*)(qp + 4);
            float x[8] = {x0[0], x0[1], x0[2], x0[3], x1[0], x1[1], x1[2], x1[3]};
            split8_reg(x, Ah[rt][c], Al[rt][c]);
        }
    float br[4][4];
#pragma unroll
    for (int rt = 0; rt < 4; ++rt)
#pragma unroll
        for (int r = 0; r < 4; ++r)
            br[rt][r] = brow[rg * 64 + rt * 16 + g * 4 + r];
    float s[4][4] = {{0.f}};
    int t0 = mblk * 64 + w * 16;
    short8 Bh0, Bh1, Bl0, Bl1;
    {
        size_t o = (size_t)t0 * 1024 + (size_t)lane * 8;
        Bh0 = *(const short8*)(bhi + o); Bh1 = *(const short8*)(bhi + o + 512);
        Bl0 = *(const short8*)(blo + o); Bl1 = *(const short8*)(blo + o + 512);
    }
#pragma unroll 4
    for (int ti = 0; ti < 16; ++ti) {
        int tn = t0 + ((ti < 15) ? ti + 1 : 15);      // clamp: harmless re-load on last iter
        size_t on = (size_t)tn * 1024 + (size_t)lane * 8;
        short8 nh0 = *(const short8*)(bhi + on);
        short8 nh1 = *(const short8*)(bhi + on + 512);
        short8 nl0 = *(const short8*)(blo + on);
        short8 nl1 = *(const short8*)(blo + on + 512);
#pragma unroll
        for (int rt = 0; rt < 4; ++rt) {
            f32x4 C = {0.f, 0.f, 0.f, 0.f};
            C = MFMA(Ah[rt][0], Bh0, C);
            C = MFMA(Ah[rt][1], Bh1, C);
            C = MFMA(Al[rt][0], Bh0, C);
            C = MFMA(Al[rt][1], Bh1, C);
            C = MFMA(Ah[rt][0], Bl0, C);
            C = MFMA(Ah[rt][1], Bl1, C);
#pragma unroll
            for (int r = 0; r < 4; ++r)
                s[rt][r] += EXP2F(C[r] - br[rt][r]);
        }
        Bh0 = nh0; Bh1 = nh1; Bl0 = nl0; Bl1 = nl1;
    }
#pragma unroll
    for (int rt = 0; rt < 4; ++rt)
#pragma unroll
        for (int r = 0; r < 4; ++r) {
            float v = s[rt][r];
            v += __shfl_xor(v, 1, 64);
            v += __shfl_xor(v, 2, 64);
            v += __shfl_xor(v, 4, 64);
            v += __shfl_xor(v, 8, 64);
            s[rt][r] = v;
        }
    if ((lane & 15) == 0) {
        int col = mblk * 4 + w;
#pragma unroll
        for (int rt = 0; rt < 4; ++rt)
#pragma unroll
            for (int r = 0; r < 4; ++r) {
                int row = rg * 64 + rt * 16 + g * 4 + r;
                psum[(size_t)row * 256 + col] = s[rt][r];
            }
    }
}

// ---------------- K4 v3: BARRIER-FREE main loop. Block = 16 rows x 4096 cols;
// wave w owns cols [w*1024, w*1024+1024) with a wave-PRIVATE 16x132 LDS tile.
// Per 128-col sub-chunk: MFMA+exp into own tile, then 512B-contiguous nt stores.
// No __syncthreads in the loop -> no forced vmcnt(0) drain: stores overlap the
// next sub-chunk's compute. (The old 2-barrier version serialized drain+compute:
// 8x(5.3+2)us ~= 59us measured.) One barrier remains after the ginv prologue. ----
__global__ __launch_bounds__(256) void k4_mfma(const unsigned short* __restrict__ bhi,
                                               const unsigned short* __restrict__ blo,
                                               const float* __restrict__ q_rm,
                                               const float* __restrict__ brow,
                                               const float* __restrict__ psum,
                                               float* __restrict__ out) {
    __shared__ float wt4[4][16 * 132];   // 33.8 KB -> 4 blocks/CU, 16 waves/CU
    __shared__ float gsh[16];
    int bx = blockIdx.x;
    int wg = ((bx & 7) << 7) | (bx >> 3);
    int mblk = wg >> 6, rg = wg & 63;       // mblk 0..15 (4096 cols), rg 0..63 (16 rows)
    int tid = threadIdx.x, w = tid >> 6, lane = tid & 63;
    int g = lane >> 4;
    // ---- fused k3: ginv for this block's 16 rows (sum 256 psum partials each) ----
    {
        int row16 = tid >> 4, seg = tid & 15;
        const float* pp = psum + (size_t)(rg * 16 + row16) * 256 + seg * 16;
        float part = 0.f;
#pragma unroll
        for (int j = 0; j < 16; ++j) part += pp[j];
#pragma unroll
        for (int off = 1; off < 16; off <<= 1) part += __shfl_xor(part, off, 64);
        if (seg == 0) gsh[row16] = 1.0f / part;
    }
    // ---- fused prep_a: A-fragments in-register from q_rm ----
    short8 Ah[2], Al[2];
#pragma unroll
    for (int c = 0; c < 2; ++c) {
        const float* qp = q_rm + (size_t)(rg * 16 + (lane & 15)) * LL
                          + c * 32 + (lane >> 4) * 8;
        f32x4 x0 = *(const f32x4*)qp, x1 = *(const f32x4*)(qp + 4);
        float x[8] = {x0[0], x0[1], x0[2], x0[3], x1[0], x1[1], x1[2], x1[3]};
        split8_reg(x, Ah[c], Al[c]);
    }
    __syncthreads();   // gsh ready (only barrier in the kernel)
    float br[4], gv[4];
#pragma unroll
    for (int r = 0; r < 4; ++r) {
        int row = rg * 16 + g * 4 + r;
        br[r] = brow[row];
        gv[r] = gsh[g * 4 + r];
    }
    float* wt = wt4[w];
    int tb = mblk * 256 + w * 64;           // wave's 64 k-tiles (1024 cols)
    short8 Bh0, Bh1, Bl0, Bl1;
    {
        size_t o = (size_t)tb * 1024 + (size_t)lane * 8;
        Bh0 = *(const short8*)(bhi + o); Bh1 = *(const short8*)(bhi + o + 512);
        Bl0 = *(const short8*)(blo + o); Bl1 = *(const short8*)(blo + o + 512);
    }
    for (int s = 0; s < 8; ++s) {
#pragma unroll
        for (int k = 0; k < 8; ++k) {
            int j = s * 8 + k;
            int jn = (j < 63) ? j + 1 : 63;     // linear prefetch (clamped re-load at end)
            size_t on = (size_t)(tb + jn) * 1024 + (size_t)lane * 8;
            short8 nh0 = *(const short8*)(bhi + on);
            short8 nh1 = *(const short8*)(bhi + on + 512);
            short8 nl0 = *(const short8*)(blo + on);
            short8 nl1 = *(const short8*)(blo + on + 512);
            f32x4 C = {0.f, 0.f, 0.f, 0.f};
            C = MFMA(Ah[0], Bh0, C);
            C = MFMA(Ah[1], Bh1, C);
            C = MFMA(Al[0], Bh0, C);
            C = MFMA(Al[1], Bh1, C);
            C = MFMA(Ah[0], Bl0, C);
            C = MFMA(Ah[1], Bl1, C);
            int cbase = k * 16 + (lane & 15);
#pragma unroll
            for (int r = 0; r < 4; ++r)
                wt[(g * 4 + r) * 132 + cbase] = EXP2F(C[r] - br[r]) * gv[r];
            Bh0 = nh0; Bh1 = nh1; Bl0 = nl0; Bl1 = nl1;
        }
        // wave-private store: 8 rounds x (2 rows x 512 B contiguous). ds_read of the
        // tile completes (lgkmcnt) before the next sub-chunk's ds_writes; global
        // stores drain in background (no vmcnt wait anywhere in the loop).
        size_t cb = (size_t)mblk * 4096 + (size_t)w * 1024 + (size_t)s * 128;
#pragma unroll
        for (int i = 0; i < 8; ++i) {
            int flat = i * 64 + lane;
            int rl = flat >> 5, slot = flat & 31;
            f32x4 v = *(const f32x4*)&wt[rl * 132 + slot * 4];
            float* dst = out + (size_t)(rg * 16 + rl) * MM + cb + (size_t)slot * 4;
            __builtin_nontemporal_store(v, (f32x4*)dst);
        }
    }
}

extern "C" void kernel_launch(void* const* d_in, const int* in_sizes, int n_in,
                              void* d_out, int out_size, void* d_ws, size_t ws_size,
                              hipStream_t stream) {
    const float* S   = (const float*)d_in[0];  // [256][2048]
    const float* mem = (const float*)d_in[1];  // [65536][64]
    const float* Wk  = (const float*)d_in[2];  // [256][2048]
    const float* bk  = (const float*)d_in[3];  // [256]
    const float* Wb  = (const float*)d_in[4];  // [4][2048]
    const float* bb  = (const float*)d_in[5];  // [4]
    float* out = (float*)d_out;                // [1024][65536]

    // workspace layout (~20 MB, all segments 16B-aligned)
    float* kpart    = (float*)d_ws;                          // 8*256*256
    float* q_rm     = kpart + (size_t)8 * BB * KEYS;         // 1024*64
    float* psum     = q_rm  + (size_t)NROW * LL;             // 1024*256
    float* brow     = psum  + (size_t)NROW * 256;            // 1024
    float* normpart = brow  + NROW;                          // 512
    unsigned short* bhi = (unsigned short*)(normpart + 512); // 8192*512
    unsigned short* blo = bhi + (size_t)8192 * 512;

    setup_k    <<<768,  256, 0, stream>>>(mem, Wk, S, bhi, blo, normpart, kpart);
    k1_finalize<<<NROW, 256, 0, stream>>>(S, kpart, bk, Wb, bb, normpart, q_rm, brow);
    k2_mfma    <<<1024, 256, 0, stream>>>(bhi, blo, q_rm, brow, psum);
    k4_mfma    <<<1024, 256, 0, stream>>>(bhi, blo, q_rm, brow, psum, out);
}

// Round 9
// 359.186 us; speedup vs baseline: 1.0798x; 1.0798x over previous
//
#include <hip/hip_runtime.h>
#include <hip/hip_bf16.h>

// Problem constants (B,R,M,L,H) = (256, 2048, 65536, 64, 4)
#define BB   256
#define RR   2048
#define MM   65536
#define LL   64
#define HH   4
#define NROW 1024      // B*H rows
#define KEYS 256       // H*L

typedef float f32x4 __attribute__((ext_vector_type(4)));
typedef short short8 __attribute__((ext_vector_type(8)));

#define MFMA(A,B,C) __builtin_amdgcn_mfma_f32_16x16x32_bf16((A),(B),(C),0,0,0)
#define LOG2E 1.4426950408889634f
#define EXP2F(x) __builtin_amdgcn_exp2f(x)

// LDS-only barrier: waits own LDS ops (lgkmcnt) then s_barrier, WITHOUT the
// vmcnt(0) drain __syncthreads carries -> global nt stores stay in flight.
// sched_barrier(0) fences both sides (guide rule #18: hipcc hoists past asm waits).
__device__ __forceinline__ void lds_barrier() {
    asm volatile("s_waitcnt lgkmcnt(0)" ::: "memory");
    __builtin_amdgcn_sched_barrier(0);
    __builtin_amdgcn_s_barrier();
    __builtin_amdgcn_sched_barrier(0);
}

// ---- bf16 round-nearest-even split helpers ----
__device__ __forceinline__ unsigned short bf16_rn(float x) {
    union { float f; unsigned int u; } v; v.f = x;
    unsigned int r = v.u + 0x7FFFu + ((v.u >> 16) & 1u);
    return (unsigned short)(r >> 16);
}
__device__ __forceinline__ float bf16_to_f(unsigned short h) {
    union { float f; unsigned int u; } v; v.u = ((unsigned int)h) << 16; return v.f;
}
__device__ __forceinline__ void split8_store(const float* x, unsigned short* hi, unsigned short* lo) {
    unsigned int ph[4], pl[4];
#pragma unroll
    for (int j = 0; j < 4; ++j) {
        unsigned short h0 = bf16_rn(x[2*j]),   l0 = bf16_rn(x[2*j]   - bf16_to_f(h0));
        unsigned short h1 = bf16_rn(x[2*j+1]), l1 = bf16_rn(x[2*j+1] - bf16_to_f(h1));
        ph[j] = (unsigned int)h0 | ((unsigned int)h1 << 16);
        pl[j] = (unsigned int)l0 | ((unsigned int)l1 << 16);
    }
    ((uint4*)hi)[0] = make_uint4(ph[0], ph[1], ph[2], ph[3]);
    ((uint4*)lo)[0] = make_uint4(pl[0], pl[1], pl[2], pl[3]);
}
// in-register variant: identical math -> bitwise-identical fragments
__device__ __forceinline__ void split8_reg(const float* x, short8& hi, short8& lo) {
    union { unsigned int u[4]; short8 s; } H, L;
#pragma unroll
    for (int j = 0; j < 4; ++j) {
        unsigned short h0 = bf16_rn(x[2*j]),   l0 = bf16_rn(x[2*j]   - bf16_to_f(h0));
        unsigned short h1 = bf16_rn(x[2*j+1]), l1 = bf16_rn(x[2*j+1] - bf16_to_f(h1));
        H.u[j] = (unsigned int)h0 | ((unsigned int)h1 << 16);
        L.u[j] = (unsigned int)l0 | ((unsigned int)l1 << 16);
    }
    hi = H.s; lo = L.s;
}

// ================= SETUP: blocks 0..511 = prep_mem, 512..767 = k0_keys ==========
__global__ __launch_bounds__(256) void setup_k(const float* __restrict__ mem,
                                               const float* __restrict__ Wk,
                                               const float* __restrict__ S,
                                               unsigned short* __restrict__ bhi,
                                               unsigned short* __restrict__ blo,
                                               float* __restrict__ normpart,
                                               float* __restrict__ kpart) {
    __shared__ float sh[18496];   // max(prep_mem: 8704+128, k0: 2048+16448) floats
    int bx = blockIdx.x, tid = threadIdx.x;
    if (bx < 512) {
        // ---------------- prep_mem ----------------
        float* t     = sh;            // [128][68]
        float* rowsq = sh + 128 * 68; // [128]
        int blk = bx;
        const f32x4* src = (const f32x4*)(mem + (size_t)blk * 128 * LL);
#pragma unroll
        for (int i = 0; i < 8; ++i) {
            int idx = i * 256 + tid;              // flat float4 index
            int row = idx >> 4, c4 = idx & 15;
            *(f32x4*)&t[row * 68 + c4 * 4] = src[idx];
        }
        __syncthreads();
        if (tid < 128) {
            const float* rp = t + tid * 68;
            float s = 0.f;
#pragma unroll
            for (int k = 0; k < 64; ++k) s = fmaf(rp[k], rp[k], s);
            rowsq[tid] = s;
        }
        __syncthreads();
        if (tid < 64) {
            float m = fmaxf(rowsq[tid], rowsq[tid + 64]);
#pragma unroll
            for (int off = 1; off < 64; off <<= 1) m = fmaxf(m, __shfl_xor(m, off, 64));
            if (tid == 0) normpart[blk] = m;
        }
#pragma unroll
        for (int i = 0; i < 4; ++i) {
            int slot = i * 256 + tid;
            int lane = slot & 63, frag_l = slot >> 6;   // frag_l 0..15
            int t_l = frag_l >> 1, c = frag_l & 1;
            int row = t_l * 16 + (lane & 15);
            int k0 = c * 32 + (lane >> 4) * 8;
            const float* p = t + row * 68 + k0;
            float x[8];
#pragma unroll
            for (int j = 0; j < 8; ++j) x[j] = p[j];
            size_t gslot = ((size_t)blk * 16 + frag_l) * 64 + lane;
            split8_store(x, bhi + gslot * 8, blo + gslot * 8);
        }
    } else {
        // ---------------- k0 keys GEMM (transpose fused) ----------------
        float* sl = sh;            // [8][256] staged S rows
        float* wk = sh + 2048;     // [64][257] transposed Wk sub-tile
        int bx2 = bx - 512;
        int bg = bx2 >> 3, kc = bx2 & 7;
        int b0 = bg * 8;
#pragma unroll
        for (int bi = 0; bi < 8; ++bi)
            sl[bi * 256 + tid] = S[(size_t)(b0 + bi) * RR + kc * 256 + tid];
        float acc[8] = {0,0,0,0,0,0,0,0};
        for (int sub = 0; sub < 4; ++sub) {
            const f32x4* wsrc = (const f32x4*)(Wk + (size_t)tid * RR + kc * 256 + sub * 64);
#pragma unroll
            for (int i = 0; i < 16; ++i) {
                f32x4 v = wsrc[i];
#pragma unroll
                for (int q = 0; q < 4; ++q)
                    wk[(i * 4 + q) * 257 + tid] = v[q];
            }
            __syncthreads();
#pragma unroll 4
            for (int kkl = 0; kkl < 64; ++kkl) {
                float wv = wk[kkl * 257 + tid];
                int kk = sub * 64 + kkl;
#pragma unroll
                for (int bi = 0; bi < 8; ++bi)
                    acc[bi] = fmaf(sl[bi * 256 + kk], wv, acc[bi]);
            }
            __syncthreads();
        }
        float* op = kpart + (size_t)kc * BB * KEYS + (size_t)b0 * KEYS + tid;
#pragma unroll
        for (int bi = 0; bi < 8; ++bi)
            op[bi * KEYS] = acc[bi];
    }
}

// ---------------- K1: beta, key norm, q_rm = keys*beta*log2e/norm, brow = beta*maxnorm*log2e ----
__global__ __launch_bounds__(256) void k1_finalize(const float* __restrict__ S,
                                                   const float* __restrict__ kpart,
                                                   const float* __restrict__ bk,
                                                   const float* __restrict__ Wb,
                                                   const float* __restrict__ bb,
                                                   const float* __restrict__ normpart,
                                                   float* __restrict__ q_rm,
                                                   float* __restrict__ brow) {
    int bh = blockIdx.x, b = bh >> 2, h = bh & 3;
    int tid = threadIdx.x, lane = tid & 63, w = tid >> 6;
    float p = 0.f;
#pragma unroll
    for (int i = 0; i < 8; ++i) {
        int k = i * 256 + tid;
        p += S[(size_t)b * RR + k] * Wb[(size_t)h * RR + k];
    }
    float nm = fmaxf(normpart[tid], normpart[256 + tid]);   // 512 partials
#pragma unroll
    for (int off = 1; off < 64; off <<= 1) {
        p  += __shfl_xor(p, off, 64);
        nm  = fmaxf(nm, __shfl_xor(nm, off, 64));
    }
    __shared__ float red[4], redm[4];
    if (lane == 0) { red[w] = p; redm[w] = nm; }
    __syncthreads();
    if (tid < 64) {
        float beta = red[0] + red[1] + red[2] + red[3] + bb[h];
        beta = fmaxf(beta, 0.f);
        float maxn = sqrtf(fmaxf(fmaxf(redm[0], redm[1]), fmaxf(redm[2], redm[3])));
        float kv = bk[h * LL + lane];
#pragma unroll
        for (int c = 0; c < 8; ++c)
            kv += kpart[(size_t)c * BB * KEYS + (size_t)b * KEYS + h * LL + lane];
        float sq = kv * kv;
#pragma unroll
        for (int off = 1; off < 64; off <<= 1) sq += __shfl_xor(sq, off, 64);
        float scale = beta * LOG2E / sqrtf(sq);
        q_rm[(size_t)bh * LL + lane] = kv * scale;
        if (lane == 0) brow[bh] = beta * maxn * LOG2E;  // exact upper bound (Cauchy-Schwarz), log2 domain
    }
}

// XCD-chunked bijective swizzle for 1024 blocks (1024 % 8 == 0)
__device__ __forceinline__ void decode_wg(int bx, int& mblk, int& rg) {
    int wg = ((bx & 7) << 7) | (bx >> 3);
    mblk = wg >> 4; rg = wg & 15;
}

// ---------------- K2: split-bf16 MFMA dot + exp2(d - brow) partial row sums ----------
__global__ __launch_bounds__(256) void k2_mfma(const unsigned short* __restrict__ bhi,
                                               const unsigned short* __restrict__ blo,
                                               const float* __restrict__ q_rm,
                                               const float* __restrict__ brow,
                                               float* __restrict__ psum) {
    int mblk, rg; decode_wg(blockIdx.x, mblk, rg);
    int tid = threadIdx.x, w = tid >> 6, lane = tid & 63;
    int g = lane >> 4;
    short8 Ah[4][2], Al[4][2];
#pragma unroll
    for (int rt = 0; rt < 4; ++rt)
#pragma unroll
        for (int c = 0; c < 2; ++c) {
            const float* qp = q_rm + (size_t)(rg * 64 + rt * 16 + (lane & 15)) * LL
                              + c * 32 + (lane >> 4) * 8;
            f32x4 x0 = *(const f32x4*)qp, x1 = *(const f32x4*)(qp + 4);
            float x[8] = {x0[0], x0[1], x0[2], x0[3], x1[0], x1[1], x1[2], x1[3]};
            split8_reg(x, Ah[rt][c], Al[rt][c]);
        }
    float br[4][4];
#pragma unroll
    for (int rt = 0; rt < 4; ++rt)
#pragma unroll
        for (int r = 0; r < 4; ++r)
            br[rt][r] = brow[rg * 64 + rt * 16 + g * 4 + r];
    float s[4][4] = {{0.f}};
    int t0 = mblk * 64 + w * 16;
    short8 Bh0, Bh1, Bl0, Bl1;
    {
        size_t o = (size_t)t0 * 1024 + (size_t)lane * 8;
        Bh0 = *(const short8*)(bhi + o); Bh1 = *(const short8*)(bhi + o + 512);
        Bl0 = *(const short8*)(blo + o); Bl1 = *(const short8*)(blo + o + 512);
    }
#pragma unroll 4
    for (int ti = 0; ti < 16; ++ti) {
        int tn = t0 + ((ti < 15) ? ti + 1 : 15);      // clamp: harmless re-load on last iter
        size_t on = (size_t)tn * 1024 + (size_t)lane * 8;
        short8 nh0 = *(const short8*)(bhi + on);
        short8 nh1 = *(const short8*)(bhi + on + 512);
        short8 nl0 = *(const short8*)(blo + on);
        short8 nl1 = *(const short8*)(blo + on + 512);
#pragma unroll
        for (int rt = 0; rt < 4; ++rt) {
            f32x4 C = {0.f, 0.f, 0.f, 0.f};
            C = MFMA(Ah[rt][0], Bh0, C);
            C = MFMA(Ah[rt][1], Bh1, C);
            C = MFMA(Al[rt][0], Bh0, C);
            C = MFMA(Al[rt][1], Bh1, C);
            C = MFMA(Ah[rt][0], Bl0, C);
            C = MFMA(Ah[rt][1], Bl1, C);
#pragma unroll
            for (int r = 0; r < 4; ++r)
                s[rt][r] += EXP2F(C[r] - br[rt][r]);
        }
        Bh0 = nh0; Bh1 = nh1; Bl0 = nl0; Bl1 = nl1;
    }
#pragma unroll
    for (int rt = 0; rt < 4; ++rt)
#pragma unroll
        for (int r = 0; r < 4; ++r) {
            float v = s[rt][r];
            v += __shfl_xor(v, 1, 64);
            v += __shfl_xor(v, 2, 64);
            v += __shfl_xor(v, 4, 64);
            v += __shfl_xor(v, 8, 64);
            s[rt][r] = v;
        }
    if ((lane & 15) == 0) {
        int col = mblk * 4 + w;
#pragma unroll
        for (int rt = 0; rt < 4; ++rt)
#pragma unroll
            for (int r = 0; r < 4; ++r) {
                int row = rg * 64 + rt * 16 + g * 4 + r;
                psum[(size_t)row * 256 + col] = s[rt][r];
            }
    }
}

// ---------------- K4 v4: block = 16 rows x 4096 cols; per 512-col chunk compute
// into 16x516 LDS then block-cooperative 2KB-contiguous nt stores (v2 geometry),
// BUT in-loop barriers are LDS-only (lgkmcnt + raw s_barrier, no vmcnt(0) drain)
// -> global nt stores drain under the next chunk's compute instead of stalling
// the whole block (v2's 59us ~= 8x(2us compute + 5.3us forced drain)). ----------
__global__ __launch_bounds__(256) void k4_mfma(const unsigned short* __restrict__ bhi,
                                               const unsigned short* __restrict__ blo,
                                               const float* __restrict__ q_rm,
                                               const float* __restrict__ brow,
                                               const float* __restrict__ psum,
                                               float* __restrict__ out) {
    __shared__ float ot[16 * 516];
    __shared__ float gsh[16];
    int bx = blockIdx.x;
    int wg = ((bx & 7) << 7) | (bx >> 3);
    int mblk = wg >> 6, rg = wg & 63;       // mblk 0..15 (4096 cols), rg 0..63 (16 rows)
    int tid = threadIdx.x, w = tid >> 6, lane = tid & 63;
    int g = lane >> 4;
    // ---- fused k3: ginv for this block's 16 rows (sum 256 psum partials each) ----
    {
        int row16 = tid >> 4, seg = tid & 15;
        const float* pp = psum + (size_t)(rg * 16 + row16) * 256 + seg * 16;
        float part = 0.f;
#pragma unroll
        for (int j = 0; j < 16; ++j) part += pp[j];
#pragma unroll
        for (int off = 1; off < 16; off <<= 1) part += __shfl_xor(part, off, 64);
        if (seg == 0) gsh[row16] = 1.0f / part;
    }
    // ---- fused prep_a: A-fragments in-register from q_rm ----
    short8 Ah[2], Al[2];
#pragma unroll
    for (int c = 0; c < 2; ++c) {
        const float* qp = q_rm + (size_t)(rg * 16 + (lane & 15)) * LL
                          + c * 32 + (lane >> 4) * 8;
        f32x4 x0 = *(const f32x4*)qp, x1 = *(const f32x4*)(qp + 4);
        float x[8] = {x0[0], x0[1], x0[2], x0[3], x1[0], x1[1], x1[2], x1[3]};
        split8_reg(x, Ah[c], Al[c]);
    }
    __syncthreads();   // gsh ready (full barrier, prologue only)
    float br[4], gv[4];
#pragma unroll
    for (int r = 0; r < 4; ++r) {
        int row = rg * 16 + g * 4 + r;
        br[r] = brow[row];
        gv[r] = gsh[g * 4 + r];
    }
    int tbase = mblk * 256 + w * 8;
    short8 Bh0, Bh1, Bl0, Bl1;
    {
        size_t o = (size_t)tbase * 1024 + (size_t)lane * 8;
        Bh0 = *(const short8*)(bhi + o); Bh1 = *(const short8*)(bhi + o + 512);
        Bl0 = *(const short8*)(blo + o); Bl1 = *(const short8*)(blo + o + 512);
    }
    for (int c = 0; c < 8; ++c) {
#pragma unroll
        for (int k = 0; k < 8; ++k) {
            int j = c * 8 + k;
            int jn = (j < 63) ? j + 1 : 63;
            int tn = tbase + (jn >> 3) * 32 + (jn & 7);
            size_t on = (size_t)tn * 1024 + (size_t)lane * 8;
            short8 nh0 = *(const short8*)(bhi + on);
            short8 nh1 = *(const short8*)(bhi + on + 512);
            short8 nl0 = *(const short8*)(blo + on);
            short8 nl1 = *(const short8*)(blo + on + 512);
            f32x4 C = {0.f, 0.f, 0.f, 0.f};
            C = MFMA(Ah[0], Bh0, C);
            C = MFMA(Ah[1], Bh1, C);
            C = MFMA(Al[0], Bh0, C);
            C = MFMA(Al[1], Bh1, C);
            C = MFMA(Ah[0], Bl0, C);
            C = MFMA(Ah[1], Bl1, C);
            int cbase = w * 128 + k * 16 + (lane & 15);
#pragma unroll
            for (int r = 0; r < 4; ++r)
                ot[(g * 4 + r) * 516 + cbase] = EXP2F(C[r] - br[r]) * gv[r];
            Bh0 = nh0; Bh1 = nh1; Bl0 = nl0; Bl1 = nl1;
        }
        lds_barrier();   // all waves' tile writes landed; nt stores NOT drained
        size_t gbase = (size_t)mblk * 4096 + (size_t)c * 512;
#pragma unroll
        for (int i = 0; i < 8; ++i) {
            int flat = i * 256 + tid;
            int rl = flat >> 7, slot = flat & 127;
            f32x4 v = *(const f32x4*)&ot[rl * 516 + slot * 4];
            float* dst = out + (size_t)(rg * 16 + rl) * MM + gbase + (size_t)slot * 4;
            __builtin_nontemporal_store(v, (f32x4*)dst);
        }
        lds_barrier();   // all waves' tile reads landed; safe to overwrite next chunk
    }
}

extern "C" void kernel_launch(void* const* d_in, const int* in_sizes, int n_in,
                              void* d_out, int out_size, void* d_ws, size_t ws_size,
                              hipStream_t stream) {
    const float* S   = (const float*)d_in[0];  // [256][2048]
    const float* mem = (const float*)d_in[1];  // [65536][64]
    const float* Wk  = (const float*)d_in[2];  // [256][2048]
    const float* bk  = (const float*)d_in[3];  // [256]
    const float* Wb  = (const float*)d_in[4];  // [4][2048]
    const float* bb  = (const float*)d_in[5];  // [4]
    float* out = (float*)d_out;                // [1024][65536]

    // workspace layout (~20 MB, all segments 16B-aligned)
    float* kpart    = (float*)d_ws;                          // 8*256*256
    float* q_rm     = kpart + (size_t)8 * BB * KEYS;         // 1024*64
    float* psum     = q_rm  + (size_t)NROW * LL;             // 1024*256
    float* brow     = psum  + (size_t)NROW * 256;            // 1024
    float* normpart = brow  + NROW;                          // 512
    unsigned short* bhi = (unsigned short*)(normpart + 512); // 8192*512
    unsigned short* blo = bhi + (size_t)8192 * 512;

    setup_k    <<<768,  256, 0, stream>>>(mem, Wk, S, bhi, blo, normpart, kpart);
    k1_finalize<<<NROW, 256, 0, stream>>>(S, kpart, bk, Wb, bb, normpart, q_rm, brow);
    k2_mfma    <<<1024, 256, 0, stream>>>(bhi, blo, q_rm, brow, psum);
    k4_mfma    <<<1024, 256, 0, stream>>>(bhi, blo, q_rm, brow, psum, out);
}